// Round 1
// baseline (222.199 us; speedup 1.0000x reference)
//
#include <hip/hip_runtime.h>
#include <math.h>

// Fused ConvTranspose3d(16->32, K=3, s=2, p=1) + MaxPool3d(6) + channel-sum.
// One block per pooled output cell (8*10*10*10 = 8000 blocks).
// y[od] window for pooled cell p: od in [6p, 6p+6); id = (od+1-kd)/2 when
// (od+1-kd) even  =>  input footprint id in [3p, 3p+3] (4^3 per ci).
// Parity classes: ud even -> tap kd=1 (dz=i); ud odd -> kd=0 (dz=i+1), kd=2 (dz=i).
// wave = uniform class set; lanes = 32 co x 2 ci-halves (shfl_xor(32) combine).

namespace {

template <int PA, int PB, int PC>
__device__ __forceinline__ float do_class(const float* __restrict__ xsl,
                                          const float* __restrict__ wsl) {
  float acc[27];
#pragma unroll
  for (int i = 0; i < 27; ++i) acc[i] = 0.f;

  constexpr int NTZ = PA ? 2 : 1;
  constexpr int NTY = PB ? 2 : 1;
  constexpr int NTX = PC ? 2 : 1;

#pragma unroll 1  // keep rolled: I-cache (full unroll ~14KB per class path)
  for (int cit = 0; cit < 8; ++cit) {
    float xr[64];
#pragma unroll
    for (int zy = 0; zy < 16; ++zy) {
      const float4 v = *reinterpret_cast<const float4*>(xsl + cit * 64 + zy * 4);
      xr[zy * 4 + 0] = v.x;
      xr[zy * 4 + 1] = v.y;
      xr[zy * 4 + 2] = v.z;
      xr[zy * 4 + 3] = v.w;
    }
    const float* wc = wsl + cit * (32 * 27);
#pragma unroll
    for (int a = 0; a < NTZ; ++a) {
      const int kd = PA ? (a == 0 ? 0 : 2) : 1;
      const int oz = PA ? (a == 0 ? 1 : 0) : 0;
#pragma unroll
      for (int b = 0; b < NTY; ++b) {
        const int kh = PB ? (b == 0 ? 0 : 2) : 1;
        const int oy = PB ? (b == 0 ? 1 : 0) : 0;
#pragma unroll
        for (int c = 0; c < NTX; ++c) {
          const int kw = PC ? (c == 0 ? 0 : 2) : 1;
          const int ox = PC ? (c == 0 ? 1 : 0) : 0;
          const float wv = wc[(kd * 3 + kh) * 3 + kw];
#pragma unroll
          for (int i = 0; i < 3; ++i)
#pragma unroll
            for (int j = 0; j < 3; ++j)
#pragma unroll
              for (int k = 0; k < 3; ++k) {
                const int p = (i * 3 + j) * 3 + k;
                acc[p] = fmaf(xr[((i + oz) * 4 + (j + oy)) * 4 + (k + ox)], wv, acc[p]);
              }
        }
      }
    }
  }
  // combine the two ci-halves (lane ^ 32), then pool-max over the 27 positions
#pragma unroll
  for (int i = 0; i < 27; ++i) acc[i] += __shfl_xor(acc[i], 32);
  float m = acc[0];
#pragma unroll
  for (int i = 1; i < 27; ++i) m = fmaxf(m, acc[i]);
  return m;
}

__global__ __launch_bounds__(256, 2) void fused_convt_pool_sum(
    const float* __restrict__ x, const float* __restrict__ w,
    const float* __restrict__ bias, float* __restrict__ out) {
  __shared__ __align__(16) float ws[16 * 32 * 27];  // 54 KB, original layout
  __shared__ __align__(16) float xs[16 * 64];       // 4 KB: [ci][4][4][4]
  __shared__ float red[4][32];

  const int t = threadIdx.x;
  const int bid = blockIdx.x;
  const int pw = bid % 10;
  const int ph = (bid / 10) % 10;
  const int pd = (bid / 100) % 10;
  const int n = bid / 1000;

  // stage weights: 13824 floats as 6912 float2 (256 thr * 27), coalesced
  {
    const float2* wg = reinterpret_cast<const float2*>(w);
    float2* wl = reinterpret_cast<float2*>(ws);
#pragma unroll
    for (int j = 0; j < 27; ++j) wl[t + 256 * j] = wg[t + 256 * j];
  }
  // stage x window: x[n][ci][3pd+z][3ph+y][3pw+xx], 1024 floats
  {
    const float* xg =
        x + (size_t)n * 16 * 32768 + (3 * pd) * 1024 + (3 * ph) * 32 + 3 * pw;
#pragma unroll
    for (int j = 0; j < 4; ++j) {
      const int e = t + 256 * j;
      const int ci = e >> 6;
      const int z = (e >> 4) & 3;
      const int y = (e >> 2) & 3;
      const int xx = e & 3;
      xs[e] = xg[ci * 32768 + z * 1024 + y * 32 + xx];
    }
  }
  __syncthreads();

  const int wave = t >> 6;
  const int cih = (t >> 5) & 1;  // which 8-ci half this half-wave handles
  const int co = t & 31;

  const float* xsl = xs + cih * 8 * 64;
  const float* wsl = ws + (cih * 8 * 32 + co) * 27;

  // class->wave assignment balances taps: w0=8, w1=4+4, w2=4+1, w3=2+2+2
  float vmax;
  if (wave == 0) {
    vmax = do_class<1, 1, 1>(xsl, wsl);
  } else if (wave == 1) {
    vmax = fmaxf(do_class<1, 1, 0>(xsl, wsl), do_class<1, 0, 1>(xsl, wsl));
  } else if (wave == 2) {
    vmax = fmaxf(do_class<0, 1, 1>(xsl, wsl), do_class<0, 0, 0>(xsl, wsl));
  } else {
    vmax = fmaxf(fmaxf(do_class<1, 0, 0>(xsl, wsl), do_class<0, 1, 0>(xsl, wsl)),
                 do_class<0, 0, 1>(xsl, wsl));
  }

  if ((t & 63) < 32) red[wave][co] = vmax;  // both halves hold identical vmax
  __syncthreads();

  if (t < 32) {
    float v = fmaxf(fmaxf(red[0][t], red[1][t]), fmaxf(red[2][t], red[3][t])) +
              bias[t];
#pragma unroll
    for (int off = 16; off > 0; off >>= 1) v += __shfl_down(v, off);
    if (t == 0) out[bid] = v;
  }
}

}  // namespace

extern "C" void kernel_launch(void* const* d_in, const int* in_sizes, int n_in,
                              void* d_out, int out_size, void* d_ws,
                              size_t ws_size, hipStream_t stream) {
  const float* x = (const float*)d_in[0];
  const float* w = (const float*)d_in[1];
  const float* b = (const float*)d_in[2];
  float* out = (float*)d_out;
  fused_convt_pool_sum<<<8000, 256, 0, stream>>>(x, w, b, out);
}

// Round 2
// 219.531 us; speedup vs baseline: 1.0122x; 1.0122x over previous
//
#include <hip/hip_runtime.h>
#include <math.h>

// Fused ConvTranspose3d(16->32, K=3, s=2, p=1) + MaxPool3d(6) + channel-sum.
// One block per pooled output cell (8*10*10*10 = 8000 blocks).
// Input footprint per pooled cell: id in [3p, 3p+3] -> 4^3 per ci (4KB LDS).
// Parity classes (8): per axis, even u -> tap k=1; odd u -> taps k=0 (off 1), k=2 (off 0).
// wave = uniform class set; lanes = 32 co x 2 ci-halves (shfl_xor(32) combine).
// Weights: pre-reordered in d_ws to [tap j][ci][co] so per-(class,tap,cit) reads
// are lane-coalesced global loads (L2-hot, double-buffered) -- no weight LDS.

namespace {

// global tap index j -> kd*9+kh*3+kw, grouped by class c = PA*4+PB*2+PC,
// within class ordered (a,b,c) with a==0 -> k=0, a==1 -> k=2 (P=1 axes).
__constant__ int JK[27] = {13, 12, 14, 10, 16, 9,  11, 15, 17, 4,  22, 3,  5, 21,
                           23, 1,  7,  19, 25, 0,  2,  6,  8,  18, 20, 24, 26};
// per-class base offset into the 27 taps: taps/class = {1,2,2,4,2,4,4,8}
// bases B[c] = {0,1,3,5,9,11,15,19}

__global__ void reorder_w(const float* __restrict__ w, float* __restrict__ w2) {
  const int o = blockIdx.x * 256 + threadIdx.x;  // 54*256 = 13824
  const int j = o >> 9;
  const int ci = (o >> 5) & 15;
  const int co = o & 31;
  w2[o] = w[(ci * 32 + co) * 27 + JK[j]];
}

template <int PA, int PB, int PC>
__device__ __forceinline__ float do_class(const float* __restrict__ xsl,
                                          const float* __restrict__ wcls) {
  constexpr int NTZ = PA ? 2 : 1;
  constexpr int NTY = PB ? 2 : 1;
  constexpr int NTX = PC ? 2 : 1;
  constexpr int NT = NTZ * NTY * NTX;
  constexpr int NZP = PA ? 4 : 3;  // x z-planes touched by this class

  float acc[27];
#pragma unroll
  for (int i = 0; i < 27; ++i) acc[i] = 0.f;

  float wc[NT];
#pragma unroll
  for (int t = 0; t < NT; ++t) wc[t] = wcls[t * 512];

#pragma unroll 1
  for (int cit = 0; cit < 8; ++cit) {
    // prefetch next ci's weights (cit=7 harmlessly re-reads cit 0)
    float wn[NT];
    const int nx = ((cit + 1) & 7) * 32;
#pragma unroll
    for (int t = 0; t < NT; ++t) wn[t] = wcls[t * 512 + nx];

    const float* xc = xsl + cit * 64;
#pragma unroll
    for (int z = 0; z < NZP; ++z) {
      float xr[16];
#pragma unroll
      for (int q = 0; q < 4; ++q) {
        const float4 v = *reinterpret_cast<const float4*>(xc + z * 16 + q * 4);
        xr[q * 4 + 0] = v.x;
        xr[q * 4 + 1] = v.y;
        xr[q * 4 + 2] = v.z;
        xr[q * 4 + 3] = v.w;
      }
#pragma unroll
      for (int a = 0; a < NTZ; ++a) {
        const int oz = PA ? (a == 0 ? 1 : 0) : 0;
        const int i = z - oz;
        if (i >= 0 && i <= 2) {  // compile-time per (z,a)
#pragma unroll
          for (int b = 0; b < NTY; ++b) {
            const int oy = PB ? (b == 0 ? 1 : 0) : 0;
#pragma unroll
            for (int c2 = 0; c2 < NTX; ++c2) {
              const int ox = PC ? (c2 == 0 ? 1 : 0) : 0;
              const float wv = wc[(a * NTY + b) * NTX + c2];
#pragma unroll
              for (int j = 0; j < 3; ++j)
#pragma unroll
                for (int k = 0; k < 3; ++k) {
                  const int p = i * 9 + j * 3 + k;
                  acc[p] = fmaf(xr[(j + oy) * 4 + (k + ox)], wv, acc[p]);
                }
            }
          }
        }
      }
    }
#pragma unroll
    for (int t = 0; t < NT; ++t) wc[t] = wn[t];
  }
  // combine the two ci-halves (lane ^ 32), then pool-max over the 27 positions
#pragma unroll
  for (int i = 0; i < 27; ++i) acc[i] += __shfl_xor(acc[i], 32);
  float m = acc[0];
#pragma unroll
  for (int i = 1; i < 27; ++i) m = fmaxf(m, acc[i]);
  return m;
}

__global__ __launch_bounds__(256, 4) void fused_convt_pool_sum(
    const float* __restrict__ x, const float* __restrict__ w2,
    const float* __restrict__ bias, float* __restrict__ out) {
  __shared__ __align__(16) float xs[16 * 64];  // 4 KB: [ci][z][y][x]
  __shared__ float red[4][32];

  const int t = threadIdx.x;
  const int bid = blockIdx.x;
  const int pw = bid % 10;
  const int ph = (bid / 10) % 10;
  const int pd = (bid / 100) % 10;
  const int n = bid / 1000;

  // stage x window: x[n][ci][3pd+z][3ph+y][3pw+xx], 1024 floats
  {
    const float* xg =
        x + (size_t)n * 16 * 32768 + (3 * pd) * 1024 + (3 * ph) * 32 + 3 * pw;
#pragma unroll
    for (int j = 0; j < 4; ++j) {
      const int e = t + 256 * j;
      const int ci = e >> 6;
      const int z = (e >> 4) & 3;
      const int y = (e >> 2) & 3;
      const int xx = e & 3;
      xs[e] = xg[ci * 32768 + z * 1024 + y * 32 + xx];
    }
  }
  __syncthreads();

  // rotate class-set assignment by block so no SIMD always gets the 8-tap set
  const int role = ((t >> 6) + bid) & 3;
  const int cih = (t >> 5) & 1;  // which 8-ci half this half-wave handles
  const int co = t & 31;

  const float* xsl = xs + cih * 8 * 64;
  const float* w2p = w2 + cih * 256 + co;  // + B[c]*512 per class

  // class->role assignment balances taps: r0=8, r1=4+4, r2=4+1, r3=2+2+2
  float vmax;
  if (role == 0) {
    vmax = do_class<1, 1, 1>(xsl, w2p + 19 * 512);
  } else if (role == 1) {
    vmax = fmaxf(do_class<1, 1, 0>(xsl, w2p + 15 * 512),
                 do_class<1, 0, 1>(xsl, w2p + 11 * 512));
  } else if (role == 2) {
    vmax = fmaxf(do_class<0, 1, 1>(xsl, w2p + 5 * 512),
                 do_class<0, 0, 0>(xsl, w2p + 0 * 512));
  } else {
    vmax = fmaxf(fmaxf(do_class<1, 0, 0>(xsl, w2p + 9 * 512),
                       do_class<0, 1, 0>(xsl, w2p + 3 * 512)),
                 do_class<0, 0, 1>(xsl, w2p + 1 * 512));
  }

  if ((t & 63) < 32) red[role][co] = vmax;  // both halves hold identical vmax
  __syncthreads();

  if (t < 32) {
    float v = fmaxf(fmaxf(red[0][t], red[1][t]), fmaxf(red[2][t], red[3][t])) +
              bias[t];
#pragma unroll
    for (int off = 16; off > 0; off >>= 1) v += __shfl_down(v, off);
    if (t == 0) out[bid] = v;
  }
}

}  // namespace

extern "C" void kernel_launch(void* const* d_in, const int* in_sizes, int n_in,
                              void* d_out, int out_size, void* d_ws,
                              size_t ws_size, hipStream_t stream) {
  const float* x = (const float*)d_in[0];
  const float* w = (const float*)d_in[1];
  const float* b = (const float*)d_in[2];
  float* out = (float*)d_out;
  float* w2 = (float*)d_ws;  // 13824 floats = 55296 B
  reorder_w<<<54, 256, 0, stream>>>(w, w2);
  fused_convt_pool_sum<<<8000, 256, 0, stream>>>(x, w2, b, out);
}

// Round 5
// 179.436 us; speedup vs baseline: 1.2383x; 1.2235x over previous
//
#include <hip/hip_runtime.h>
#include <math.h>

// Fused ConvTranspose3d(16->32, K=3, s=2, p=1) + MaxPool3d(6) + channel-sum.
// One block per pooled output cell (8*10*10*10 = 8000 blocks).
// Input footprint per pooled cell: id in [3p, 3p+3] -> 4^3 per ci (4KB LDS).
// Parity classes (8): per axis, even u -> tap k=1; odd u -> taps k=0 (off 1), k=2 (off 0).
// Each wave handles a COMPLEMENT PAIR of classes {c, 7^c} in ONE sweep over
// (ci, z-plane) -> x is read from LDS once per wave (512 b128/block total).
// lanes = 32 co x 2 ci-halves (shfl_xor(32) combine before pool-max).
// Weights pre-reordered in d_ws to [tap j][ci][co]: per-(tap,ci) reads are
// lane-coalesced global loads (L2-hot, double-buffered across ci).

namespace {

// global tap index j -> kd*9+kh*3+kw, grouped by class c = PA*4+PB*2+PC,
// within class ordered (a,b,c) with a==0 -> k=0, a==1 -> k=2 (P=1 axes).
__constant__ int JK[27] = {13, 12, 14, 10, 16, 9,  11, 15, 17, 4,  22, 3,  5, 21,
                           23, 1,  7,  19, 25, 0,  2,  6,  8,  18, 20, 24, 26};
// class tap-counts {1,2,2,4,2,4,4,8}; bases B[c] = {0,1,3,5,9,11,15,19}

__global__ void reorder_w(const float* __restrict__ w, float* __restrict__ w2) {
  const int o = blockIdx.x * 256 + threadIdx.x;  // 54*256 = 13824
  const int j = o >> 9;
  const int ci = (o >> 5) & 15;
  const int co = o & 31;
  w2[o] = w[(ci * 32 + co) * 27 + JK[j]];
}

template <int PA, int PB, int PC, int NT>
__device__ __forceinline__ void apply_plane(const int z, const float xr[16],
                                            const float wv[NT], float acc[27]) {
  constexpr int NTZ = PA ? 2 : 1;
  constexpr int NTY = PB ? 2 : 1;
  constexpr int NTX = PC ? 2 : 1;
#pragma unroll
  for (int a = 0; a < NTZ; ++a) {
    const int oz = PA ? (a == 0 ? 1 : 0) : 0;
    const int i = z - oz;
    if (i >= 0 && i <= 2) {  // folds at compile time (z unrolled)
#pragma unroll
      for (int b = 0; b < NTY; ++b) {
        const int oy = PB ? (b == 0 ? 1 : 0) : 0;
#pragma unroll
        for (int c2 = 0; c2 < NTX; ++c2) {
          const int ox = PC ? (c2 == 0 ? 1 : 0) : 0;
          const float w = wv[(a * NTY + b) * NTX + c2];
#pragma unroll
          for (int j = 0; j < 3; ++j)
#pragma unroll
            for (int k = 0; k < 3; ++k) {
              const int p = i * 9 + j * 3 + k;
              acc[p] = fmaf(xr[(j + oy) * 4 + (k + ox)], w, acc[p]);
            }
        }
      }
    }
  }
}

template <int CA>
__device__ __forceinline__ float do_pair(const float* __restrict__ xsl,
                                         const float* __restrict__ wA,
                                         const float* __restrict__ wB) {
  constexpr int CB = 7 ^ CA;
  constexpr int PAa = (CA >> 2) & 1, PBa = (CA >> 1) & 1, PCa = CA & 1;
  constexpr int PAb = (CB >> 2) & 1, PBb = (CB >> 1) & 1, PCb = CB & 1;
  constexpr int NTA = (PAa ? 2 : 1) * (PBa ? 2 : 1) * (PCa ? 2 : 1);
  constexpr int NTB = (PAb ? 2 : 1) * (PBb ? 2 : 1) * (PCb ? 2 : 1);

  float accA[27], accB[27];
#pragma unroll
  for (int i = 0; i < 27; ++i) accA[i] = accB[i] = 0.f;

  float wa[NTA], wb[NTB];
#pragma unroll
  for (int t = 0; t < NTA; ++t) wa[t] = wA[t * 512];
#pragma unroll
  for (int t = 0; t < NTB; ++t) wb[t] = wB[t * 512];

#pragma unroll 1
  for (int cit = 0; cit < 8; ++cit) {
    // prefetch next ci's weights (cit=7 harmlessly re-reads ci 0)
    float wna[NTA], wnb[NTB];
    const int nx = ((cit + 1) & 7) * 32;
#pragma unroll
    for (int t = 0; t < NTA; ++t) wna[t] = wA[t * 512 + nx];
#pragma unroll
    for (int t = 0; t < NTB; ++t) wnb[t] = wB[t * 512 + nx];

    const float* xc = xsl + cit * 64;
#pragma unroll
    for (int z = 0; z < 4; ++z) {
      float xr[16];
#pragma unroll
      for (int q = 0; q < 4; ++q) {
        const float4 v = *reinterpret_cast<const float4*>(xc + z * 16 + q * 4);
        xr[q * 4 + 0] = v.x;
        xr[q * 4 + 1] = v.y;
        xr[q * 4 + 2] = v.z;
        xr[q * 4 + 3] = v.w;
      }
      apply_plane<PAa, PBa, PCa, NTA>(z, xr, wa, accA);
      apply_plane<PAb, PBb, PCb, NTB>(z, xr, wb, accB);
    }
#pragma unroll
    for (int t = 0; t < NTA; ++t) wa[t] = wna[t];
#pragma unroll
    for (int t = 0; t < NTB; ++t) wb[t] = wnb[t];
  }
  // combine the two ci-halves (lane ^ 32), then pool-max over positions
#pragma unroll
  for (int i = 0; i < 27; ++i) accA[i] += __shfl_xor(accA[i], 32);
#pragma unroll
  for (int i = 0; i < 27; ++i) accB[i] += __shfl_xor(accB[i], 32);
  float m = fmaxf(accA[0], accB[0]);
#pragma unroll
  for (int i = 1; i < 27; ++i) m = fmaxf(m, fmaxf(accA[i], accB[i]));
  return m;
}

__global__ __launch_bounds__(256, 2) void fused_convt_pool_sum(
    const float* __restrict__ x, const float* __restrict__ w2,
    const float* __restrict__ bias, float* __restrict__ out) {
  __shared__ __align__(16) float xs[16 * 64];  // 4 KB: [ci][z][y][x]
  __shared__ float red[4][32];

  const int t = threadIdx.x;
  const int bid = blockIdx.x;
  const int pw = bid % 10;
  const int ph = (bid / 10) % 10;
  const int pd = (bid / 100) % 10;
  const int n = bid / 1000;

  // stage x window: x[n][ci][3pd+z][3ph+y][3pw+xx], 1024 floats
  {
    const float* xg =
        x + (size_t)n * 16 * 32768 + (3 * pd) * 1024 + (3 * ph) * 32 + 3 * pw;
#pragma unroll
    for (int j = 0; j < 4; ++j) {
      const int e = t + 256 * j;
      const int ci = e >> 6;
      const int z = (e >> 4) & 3;
      const int y = (e >> 2) & 3;
      const int xx = e & 3;
      xs[e] = xg[ci * 32768 + z * 1024 + y * 32 + xx];
    }
  }
  __syncthreads();

  // rotate pair assignment by block so no SIMD always gets the 9-tap pair
  const int role = ((t >> 6) + bid) & 3;
  const int cih = (t >> 5) & 1;  // which 8-ci half this half-wave handles
  const int co = t & 31;

  const float* xsl = xs + cih * 8 * 64;
  const float* w2p = w2 + cih * 256 + co;  // + B[c]*512 per class

  // complement pairs: {c7,c0}=9, {c6,c1}=6, {c5,c2}=6, {c3,c4}=6 taps
  float vmax;
  if (role == 0) {
    vmax = do_pair<7>(xsl, w2p + 19 * 512, w2p + 0 * 512);
  } else if (role == 1) {
    vmax = do_pair<6>(xsl, w2p + 15 * 512, w2p + 1 * 512);
  } else if (role == 2) {
    vmax = do_pair<5>(xsl, w2p + 11 * 512, w2p + 3 * 512);
  } else {
    vmax = do_pair<3>(xsl, w2p + 5 * 512, w2p + 9 * 512);
  }

  if ((t & 63) < 32) red[role][co] = vmax;  // both halves hold identical vmax
  __syncthreads();

  if (t < 32) {
    float v = fmaxf(fmaxf(red[0][t], red[1][t]), fmaxf(red[2][t], red[3][t])) +
              bias[t];
#pragma unroll
    for (int off = 16; off > 0; off >>= 1) v += __shfl_down(v, off);
    if (t == 0) out[bid] = v;
  }
}

}  // namespace

extern "C" void kernel_launch(void* const* d_in, const int* in_sizes, int n_in,
                              void* d_out, int out_size, void* d_ws,
                              size_t ws_size, hipStream_t stream) {
  const float* x = (const float*)d_in[0];
  const float* w = (const float*)d_in[1];
  const float* b = (const float*)d_in[2];
  float* out = (float*)d_out;
  float* w2 = (float*)d_ws;  // 13824 floats = 55296 B
  reorder_w<<<54, 256, 0, stream>>>(w, w2);
  fused_convt_pool_sum<<<8000, 256, 0, stream>>>(x, w2, b, out);
}

// Round 6
// 82.300 us; speedup vs baseline: 2.6999x; 2.1803x over previous
//
#include <hip/hip_runtime.h>
#include <hip/hip_bf16.h>
#include <math.h>

// Fused ConvTranspose3d(16->32, K=3, s=2, p=1) + MaxPool3d(6) + channel-sum,
// MFMA edition. One WAVE per pooled cell (8000 cells, 2000 blocks x 4 waves,
// no cross-wave LDS sharing -> no __syncthreads).
//
// Per class c (output parity), y[pos(27) x co(32)] = sum_{taps of c} A_t * B_t
// with A_t[27x16ci] gathered from the cell's 4^3 x-window and B_t[16ci x 32co]
// the tap's weight slice -> one v_mfma_f32_32x32x16_bf16 per tap (27 total).
// D layout (verified m74/m101): col = lane&31 (=co), row = (reg&3)+8*(reg>>2)
// +4*(lane>>5) (=position). Rows 27..31 invalid -> masked in max-reduce.
// A/B input layout: M(or N) = lane&31, k = 8*(lane>>5)+i (8 contiguous bf16).
//
// x LDS layout: [g = zi*16+yi*4+xi][ci] bf16, 48B stride per g, byte addr
// (g*48 + cihalf*16 + (ci&7)*2) ^ ((zi&3)<<4)  -> A-reads <=2-way conflicts.
// Weights: prep kernel writes [tap][khalf][co][8ci] bf16 to d_ws; each wave
// holds all 27 B-frags in VGPRs (108), loaded once, L2-hot.

namespace {

typedef __attribute__((ext_vector_type(8))) short short8;
typedef __attribute__((ext_vector_type(16))) float f32x16;

__device__ __forceinline__ uint f2bf(float f) {
  uint u = __float_as_uint(f);
  return (u + 0x7FFFu + ((u >> 16) & 1u)) >> 16;  // RNE bf16 bits
}

__global__ void prep_w(const float* __restrict__ w, ushort* __restrict__ w2) {
  const int o = blockIdx.x * 256 + threadIdx.x;  // 27*2*32*8 = 13824
  const int j = o >> 9;          // tap kd*9+kh*3+kw
  const int cih = (o >> 8) & 1;  // k-half
  const int co = (o >> 3) & 31;
  const int ci = cih * 8 + (o & 7);
  w2[o] = (ushort)f2bf(w[(ci * 32 + co) * 27 + j]);
}

template <int PA, int PB, int PC>
__device__ __forceinline__ float cls_max(const short8 (&bq)[27],
                                         const char* __restrict__ xw, int lin0,
                                         int lin1, int sz0, int sz1, int hi) {
  f32x16 d;
#pragma unroll
  for (int i = 0; i < 16; ++i) d[i] = 0.f;
#pragma unroll
  for (int a = 0; a < (PA ? 2 : 1); ++a) {
    const int kd = PA ? (a ? 2 : 0) : 1;
    const int oz = PA ? (a ? 0 : 1) : 0;
#pragma unroll
    for (int b = 0; b < (PB ? 2 : 1); ++b) {
      const int kh = PB ? (b ? 2 : 0) : 1;
      const int oy = PB ? (b ? 0 : 1) : 0;
#pragma unroll
      for (int c = 0; c < (PC ? 2 : 1); ++c) {
        const int kw = PC ? (c ? 2 : 0) : 1;
        const int ox = PC ? (c ? 0 : 1) : 0;
        // XOR swizzle applied AFTER the linear tap offset (oy,ox don't carry
        // into g's z-bits since j+oy<=3, k+ox<=3)
        const int addr =
            ((oz ? lin1 : lin0) + (oy * 4 + ox) * 48) ^ (oz ? sz1 : sz0);
        const short8 av = *reinterpret_cast<const short8*>(xw + addr);
        d = __builtin_amdgcn_mfma_f32_32x32x16_bf16(av, bq[kd * 9 + kh * 3 + kw],
                                                    d, 0, 0, 0);
      }
    }
  }
  // max over valid rows: regs 0..11 valid both halves; 12..14 only hi==0;
  // reg 15 never (rows 27 / 31).
  float ma = d[0];
#pragma unroll
  for (int i = 1; i < 12; ++i) ma = fmaxf(ma, d[i]);
  const float mb = fmaxf(d[12], fmaxf(d[13], d[14]));
  float vm = hi ? ma : fmaxf(ma, mb);
  vm = fmaxf(vm, __shfl_xor(vm, 32));  // combine row-halves (same col)
  return vm;
}

__global__ __launch_bounds__(256, 2) void fused_mfma(
    const float* __restrict__ x, const ushort* __restrict__ w2,
    const float* __restrict__ bias, float* __restrict__ out) {
  __shared__ __align__(16) char xls[4 * 3072];

  const int t = threadIdx.x;
  const int wv = t >> 6;
  const int l = t & 63;
  const int hi = l >> 5;
  const int co = l & 31;

  const int cell = blockIdx.x * 4 + wv;
  const int pw = cell % 10;
  const int ph = (cell / 10) % 10;
  const int pd = (cell / 100) % 10;
  const int n = cell / 1000;

  // all 27 B-fragments in VGPRs (16B coalesced loads, L2-hot)
  short8 bq[27];
#pragma unroll
  for (int tp = 0; tp < 27; ++tp)
    bq[tp] = *reinterpret_cast<const short8*>(w2 + tp * 512 + hi * 256 + co * 8);

  // stage this wave's 4^3 x-window: lane = spatial g, gathers its 16 ci
  char* xw = xls + wv * 3072;
  {
    const int xi = l & 3, yi = (l >> 2) & 3, zi = l >> 4;
    const float* xg = x + (size_t)n * 524288 + (size_t)(3 * pd + zi) * 1024 +
                      (3 * ph + yi) * 32 + (3 * pw + xi);
    uint pk[8];
#pragma unroll
    for (int q = 0; q < 8; ++q) {
      const uint h0 = f2bf(xg[(2 * q) * 32768]);
      const uint h1 = f2bf(xg[(2 * q + 1) * 32768]);
      pk[q] = (h0 & 0xFFFFu) | (h1 << 16);
    }
    const int swz = (zi & 3) << 4;
    const int a0 = (l * 48) ^ swz;        // ci 0..7
    const int a1 = (l * 48 + 16) ^ swz;   // ci 8..15
    *reinterpret_cast<uint4*>(xw + a0) = make_uint4(pk[0], pk[1], pk[2], pk[3]);
    *reinterpret_cast<uint4*>(xw + a1) = make_uint4(pk[4], pk[5], pk[6], pk[7]);
  }
  // wave-internal RAW on LDS (no cross-wave sharing): drain writes
  asm volatile("s_waitcnt lgkmcnt(0)" ::: "memory");

  // per-lane A base addresses: position p = lane&31 (rows 27..31 dup p=26)
  int p = co > 26 ? 26 : co;
  const int ip = p / 9, jp = (p / 3) % 3, kp = p % 3;
  const int lin0 = (ip * 16 + jp * 4 + kp) * 48 + hi * 16;        // oz = 0
  const int lin1 = ((ip + 1) * 16 + jp * 4 + kp) * 48 + hi * 16;  // oz = 1
  const int sz0 = (ip & 3) << 4;
  const int sz1 = ((ip + 1) & 3) << 4;

  float cm = cls_max<0, 0, 0>(bq, xw, lin0, lin1, sz0, sz1, hi);
  cm = fmaxf(cm, cls_max<0, 0, 1>(bq, xw, lin0, lin1, sz0, sz1, hi));
  cm = fmaxf(cm, cls_max<0, 1, 0>(bq, xw, lin0, lin1, sz0, sz1, hi));
  cm = fmaxf(cm, cls_max<0, 1, 1>(bq, xw, lin0, lin1, sz0, sz1, hi));
  cm = fmaxf(cm, cls_max<1, 0, 0>(bq, xw, lin0, lin1, sz0, sz1, hi));
  cm = fmaxf(cm, cls_max<1, 0, 1>(bq, xw, lin0, lin1, sz0, sz1, hi));
  cm = fmaxf(cm, cls_max<1, 1, 0>(bq, xw, lin0, lin1, sz0, sz1, hi));
  cm = fmaxf(cm, cls_max<1, 1, 1>(bq, xw, lin0, lin1, sz0, sz1, hi));

  // + bias, then sum over the 32 channels (both halves hold identical data)
  float r = cm + bias[co];
#pragma unroll
  for (int off = 16; off >= 1; off >>= 1) r += __shfl_xor(r, off);
  if (l == 0) out[cell] = r;
}

}  // namespace

extern "C" void kernel_launch(void* const* d_in, const int* in_sizes, int n_in,
                              void* d_out, int out_size, void* d_ws,
                              size_t ws_size, hipStream_t stream) {
  const float* x = (const float*)d_in[0];
  const float* w = (const float*)d_in[1];
  const float* b = (const float*)d_in[2];
  float* out = (float*)d_out;
  ushort* w2 = (ushort*)d_ws;  // 13824 ushort = 27648 B
  prep_w<<<54, 256, 0, stream>>>(w, w2);
  fused_mfma<<<2000, 256, 0, stream>>>(x, w2, b, out);
}

// Round 7
// 81.957 us; speedup vs baseline: 2.7112x; 1.0042x over previous
//
#include <hip/hip_runtime.h>
#include <hip/hip_bf16.h>
#include <math.h>

// Fused ConvTranspose3d(16->32, K=3, s=2, p=1) + MaxPool3d(6) + channel-sum,
// MFMA edition. One WAVE per pooled cell (8000 cells, 2000 blocks x 4 waves).
// Per class c (output parity), y[pos(27) x co(32)] = sum_{taps of c} A_t * B_t,
// A_t[27x16ci] from the cell's 4^3 x-window (LDS, XOR-swizzled), B_t[16ci x
// 32co] the tap's weights -> one v_mfma_f32_32x32x16_bf16 per tap (27 total).
// D layout (m74/m101): col = lane&31 (=co), row = (reg&3)+8*(reg>>2)+4*hi.
// Rows 27..31 invalid -> masked in max-reduce.
// B-frags are loaded PER CLASS (<=8 live short8 = 32 VGPR, vs 108 for all 27)
// so the kernel fits __launch_bounds__(256,4) -> 2x occupancy vs R6.
// w2 layout (prep_w): [class-ordered tap][khalf][co][8ci] bf16 -> per-tap
// lane-coalesced 1KB loads, L1-hot (13.8KB total).

namespace {

typedef __attribute__((ext_vector_type(8))) short short8;
typedef __attribute__((ext_vector_type(16))) float f32x16;

// class-ordered tap -> kd*9+kh*3+kw; class c=PA*4+PB*2+PC, within-class
// (a,b,c) with a==0 -> k=0, a==1 -> k=2 on P=1 axes. bases {0,1,3,5,9,11,15,19}
__constant__ int JK[27] = {13, 12, 14, 10, 16, 9,  11, 15, 17, 4,  22, 3,  5, 21,
                           23, 1,  7,  19, 25, 0,  2,  6,  8,  18, 20, 24, 26};

__device__ __forceinline__ uint f2bf(float f) {
  uint u = __float_as_uint(f);
  return (u + 0x7FFFu + ((u >> 16) & 1u)) >> 16;  // RNE bf16 bits
}

__global__ void prep_w(const float* __restrict__ w, ushort* __restrict__ w2) {
  const int o = blockIdx.x * 256 + threadIdx.x;  // 27*2*32*8 = 13824
  const int t2 = o >> 9;         // class-ordered tap
  const int cih = (o >> 8) & 1;  // k-half
  const int co = (o >> 3) & 31;
  const int ci = cih * 8 + (o & 7);
  w2[o] = (ushort)f2bf(w[(ci * 32 + co) * 27 + JK[t2]]);
}

template <int PA, int PB, int PC, int BASE>
__device__ __forceinline__ float cls_max(const ushort* __restrict__ w2l,
                                         const char* __restrict__ xw, int lin0,
                                         int lin1, int sz0, int sz1, int hi) {
  constexpr int NTZ = PA ? 2 : 1, NTY = PB ? 2 : 1, NTX = PC ? 2 : 1;
  constexpr int NT = NTZ * NTY * NTX;
  short8 bv[NT];
#pragma unroll
  for (int t = 0; t < NT; ++t)
    bv[t] = *reinterpret_cast<const short8*>(w2l + (BASE + t) * 512);

  f32x16 d;
#pragma unroll
  for (int i = 0; i < 16; ++i) d[i] = 0.f;
#pragma unroll
  for (int a = 0; a < NTZ; ++a) {
    const int oz = PA ? (a ? 0 : 1) : 0;
#pragma unroll
    for (int b = 0; b < NTY; ++b) {
      const int oy = PB ? (b ? 0 : 1) : 0;
#pragma unroll
      for (int c = 0; c < NTX; ++c) {
        const int ox = PC ? (c ? 0 : 1) : 0;
        // XOR swizzle applied AFTER the linear tap offset (oy,ox stay in-plane)
        const int addr =
            ((oz ? lin1 : lin0) + (oy * 4 + ox) * 48) ^ (oz ? sz1 : sz0);
        const short8 av = *reinterpret_cast<const short8*>(xw + addr);
        d = __builtin_amdgcn_mfma_f32_32x32x16_bf16(
            av, bv[(a * NTY + b) * NTX + c], d, 0, 0, 0);
      }
    }
  }
  // max over valid rows: regs 0..11 valid both halves; 12..14 only hi==0.
  float ma = d[0];
#pragma unroll
  for (int i = 1; i < 12; ++i) ma = fmaxf(ma, d[i]);
  const float mb = fmaxf(d[12], fmaxf(d[13], d[14]));
  return hi ? ma : fmaxf(ma, mb);
}

__global__ __launch_bounds__(256, 4) void fused_mfma(
    const float* __restrict__ x, const ushort* __restrict__ w2,
    const float* __restrict__ bias, float* __restrict__ out) {
  __shared__ __align__(16) char xls[4 * 3072];

  const int t = threadIdx.x;
  const int wv = t >> 6;
  const int l = t & 63;
  const int hi = l >> 5;
  const int co = l & 31;

  const int cell = blockIdx.x * 4 + wv;
  const int pw = cell % 10;
  const int ph = (cell / 10) % 10;
  const int pd = (cell / 100) % 10;
  const int n = cell / 1000;

  // stage this wave's 4^3 x-window: lane = spatial g, gathers its 16 ci
  char* xw = xls + wv * 3072;
  {
    const int xi = l & 3, yi = (l >> 2) & 3, zi = l >> 4;
    const float* xg = x + (size_t)n * 524288 + (size_t)(3 * pd + zi) * 1024 +
                      (3 * ph + yi) * 32 + (3 * pw + xi);
    uint pk[8];
#pragma unroll
    for (int q = 0; q < 8; ++q) {
      const uint h0 = f2bf(xg[(2 * q) * 32768]);
      const uint h1 = f2bf(xg[(2 * q + 1) * 32768]);
      pk[q] = (h0 & 0xFFFFu) | (h1 << 16);
    }
    const int swz = (zi & 3) << 4;
    const int a0 = (l * 48) ^ swz;       // ci 0..7
    const int a1 = (l * 48 + 16) ^ swz;  // ci 8..15
    *reinterpret_cast<uint4*>(xw + a0) = make_uint4(pk[0], pk[1], pk[2], pk[3]);
    *reinterpret_cast<uint4*>(xw + a1) = make_uint4(pk[4], pk[5], pk[6], pk[7]);
  }
  // wave-internal RAW on LDS (no cross-wave sharing): drain writes
  asm volatile("s_waitcnt lgkmcnt(0)" ::: "memory");

  // per-lane A base addresses: position p = lane&31 (rows 27..31 dup p=26)
  int p = co > 26 ? 26 : co;
  const int ip = p / 9, jp = (p / 3) % 3, kp = p % 3;
  const int lin0 = (ip * 16 + jp * 4 + kp) * 48 + hi * 16;        // oz = 0
  const int lin1 = ((ip + 1) * 16 + jp * 4 + kp) * 48 + hi * 16;  // oz = 1
  const int sz0 = (ip & 3) << 4;
  const int sz1 = ((ip + 1) & 3) << 4;

  const ushort* w2l = w2 + hi * 256 + co * 8;

  float cm = cls_max<1, 1, 1, 19>(w2l, xw, lin0, lin1, sz0, sz1, hi);
  cm = fmaxf(cm, cls_max<1, 1, 0, 15>(w2l, xw, lin0, lin1, sz0, sz1, hi));
  cm = fmaxf(cm, cls_max<1, 0, 1, 11>(w2l, xw, lin0, lin1, sz0, sz1, hi));
  cm = fmaxf(cm, cls_max<1, 0, 0, 9>(w2l, xw, lin0, lin1, sz0, sz1, hi));
  cm = fmaxf(cm, cls_max<0, 1, 1, 5>(w2l, xw, lin0, lin1, sz0, sz1, hi));
  cm = fmaxf(cm, cls_max<0, 1, 0, 3>(w2l, xw, lin0, lin1, sz0, sz1, hi));
  cm = fmaxf(cm, cls_max<0, 0, 1, 1>(w2l, xw, lin0, lin1, sz0, sz1, hi));
  cm = fmaxf(cm, cls_max<0, 0, 0, 0>(w2l, xw, lin0, lin1, sz0, sz1, hi));
  cm = fmaxf(cm, __shfl_xor(cm, 32));  // combine row-halves (same col)

  // + bias, then sum over the 32 channels (both halves hold identical data)
  float r = cm + bias[co];
#pragma unroll
  for (int off = 16; off >= 1; off >>= 1) r += __shfl_xor(r, off);
  if (l == 0) out[cell] = r;
}

}  // namespace

extern "C" void kernel_launch(void* const* d_in, const int* in_sizes, int n_in,
                              void* d_out, int out_size, void* d_ws,
                              size_t ws_size, hipStream_t stream) {
  const float* x = (const float*)d_in[0];
  const float* w = (const float*)d_in[1];
  const float* b = (const float*)d_in[2];
  float* out = (float*)d_out;
  ushort* w2 = (ushort*)d_ws;  // 13824 ushort = 27648 B
  prep_w<<<54, 256, 0, stream>>>(w, w2);
  fused_mfma<<<2000, 256, 0, stream>>>(x, w2, b, out);
}